// Round 1
// baseline (185.860 us; speedup 1.0000x reference)
//
#include <hip/hip_runtime.h>
#include <math.h>

#define TOPK 4

__global__ __launch_bounds__(256) void segment_top4_kernel(
    const int* __restrict__ row_ptr,
    const float* __restrict__ scores,
    float* __restrict__ vals_out,   // [N,4] float32
    float* __restrict__ idx_out,    // [N,4] indices written as float32
    int n_nodes)
{
    int node = blockIdx.x * blockDim.x + threadIdx.x;
    if (node >= n_nodes) return;

    int seg_beg = row_ptr[node];
    int seg_end = row_ptr[node + 1];

    float v0 = -INFINITY, v1 = -INFINITY, v2 = -INFINITY, v3 = -INFINITY;
    int   i0 = -1, i1 = -1, i2 = -1, i3 = -1;

    // Branchless insertion, strict '>' so ties keep the smaller (earlier) edge
    // index — matches the reference's tie-break semantics.
    auto ins = [&](float sc, int id) {
        bool g0 = sc > v0, g1 = sc > v1, g2 = sc > v2, g3 = sc > v3;
        v3 = g3 ? (g2 ? v2 : sc) : v3;  i3 = g3 ? (g2 ? i2 : id) : i3;
        v2 = g2 ? (g1 ? v1 : sc) : v2;  i2 = g2 ? (g1 ? i1 : id) : i2;
        v1 = g1 ? (g0 ? v0 : sc) : v1;  i1 = g1 ? (g0 ? i0 : id) : i1;
        v0 = g0 ? sc : v0;              i0 = g0 ? id : i0;
    };

    int p = seg_beg;
    // Scalar head until 16B-aligned (scores base is allocation-aligned).
    int aligned = (seg_beg + 3) & ~3;
    if (aligned > seg_end) aligned = seg_end;
    for (; p < aligned; ++p) ins(scores[p], p);
    // float4 body.
    for (; p + 4 <= seg_end; p += 4) {
        float4 q = *(const float4*)(scores + p);
        ins(q.x, p); ins(q.y, p + 1); ins(q.z, p + 2); ins(q.w, p + 3);
    }
    // Scalar tail.
    for (; p < seg_end; ++p) ins(scores[p], p);

    float4 vout = make_float4(v0, v1, v2, v3);
    *(float4*)(vals_out + (size_t)node * 4) = vout;
    float4 iout = make_float4((float)i0, (float)i1, (float)i2, (float)i3);
    *(float4*)(idx_out + (size_t)node * 4) = iout;
}

extern "C" void kernel_launch(void* const* d_in, const int* in_sizes, int n_in,
                              void* d_out, int out_size, void* d_ws, size_t ws_size,
                              hipStream_t stream)
{
    const int*   row_ptr = (const int*)d_in[0];
    const float* scores  = (const float*)d_in[1];
    int n_nodes = in_sizes[0] - 1;

    float* out      = (float*)d_out;
    float* vals_out = out;                           // first N*4 floats
    float* idx_out  = out + (size_t)n_nodes * TOPK;  // next N*4 floats (idx as f32)

    int threads = 256;
    int blocks  = (n_nodes + threads - 1) / threads;
    segment_top4_kernel<<<blocks, threads, 0, stream>>>(
        row_ptr, scores, vals_out, idx_out, n_nodes);
}

// Round 2
// 169.136 us; speedup vs baseline: 1.0989x; 1.0989x over previous
//
#include <hip/hip_runtime.h>
#include <math.h>

#define TOPK 4

__global__ __launch_bounds__(256) void segment_top4_kernel(
    const int* __restrict__ row_ptr,
    const float* __restrict__ scores,
    float* __restrict__ vals_out,   // [N,4] float32
    float* __restrict__ idx_out,    // [N,4] indices written as float32
    int n_nodes)
{
    int node = blockIdx.x * blockDim.x + threadIdx.x;
    if (node >= n_nodes) return;

    int seg_beg = row_ptr[node];
    int seg_end = row_ptr[node + 1];

    float v0 = -INFINITY, v1 = -INFINITY, v2 = -INFINITY, v3 = -INFINITY;
    int   i0 = -1, i1 = -1, i2 = -1, i3 = -1;

    // Branchless insertion, strict '>' so ties keep the smaller (earlier) edge
    // index — matches the reference's tie-break. sc = -inf never inserts.
    auto ins = [&](float sc, int id) {
        bool g0 = sc > v0, g1 = sc > v1, g2 = sc > v2, g3 = sc > v3;
        v3 = g3 ? (g2 ? v2 : sc) : v3;  i3 = g3 ? (g2 ? i2 : id) : i3;
        v2 = g2 ? (g1 ? v1 : sc) : v2;  i2 = g2 ? (g1 ? i1 : id) : i2;
        v1 = g1 ? (g0 ? v0 : sc) : v1;  i1 = g1 ? (g0 ? i0 : id) : i1;
        v0 = g0 ? sc : v0;              i0 = g0 ? id : i0;
    };

    // Full-cache-line iteration: 16 floats (64 B) per step, 4x float4 loads
    // issued back-to-back so each HBM line is consumed exactly once per lane
    // regardless of cache retention. Out-of-segment elements masked to -inf.
    // N_EDGES is a multiple of 16, so the last line never runs off the array.
    for (int p = seg_beg & ~15; p < seg_end; p += 16) {
        const float4* q4 = (const float4*)(scores + p);
        float4 a = q4[0];
        float4 b = q4[1];
        float4 c = q4[2];
        float4 d = q4[3];
        float s[16] = {a.x, a.y, a.z, a.w,
                       b.x, b.y, b.z, b.w,
                       c.x, c.y, c.z, c.w,
                       d.x, d.y, d.z, d.w};
        #pragma unroll
        for (int j = 0; j < 16; ++j) {
            int e = p + j;
            bool in_seg = (e >= seg_beg) & (e < seg_end);
            ins(in_seg ? s[j] : -INFINITY, e);
        }
    }

    float4 vout = make_float4(v0, v1, v2, v3);
    *(float4*)(vals_out + (size_t)node * 4) = vout;
    float4 iout = make_float4((float)i0, (float)i1, (float)i2, (float)i3);
    *(float4*)(idx_out + (size_t)node * 4) = iout;
}

extern "C" void kernel_launch(void* const* d_in, const int* in_sizes, int n_in,
                              void* d_out, int out_size, void* d_ws, size_t ws_size,
                              hipStream_t stream)
{
    const int*   row_ptr = (const int*)d_in[0];
    const float* scores  = (const float*)d_in[1];
    int n_nodes = in_sizes[0] - 1;

    float* out      = (float*)d_out;
    float* vals_out = out;                           // first N*4 floats
    float* idx_out  = out + (size_t)n_nodes * TOPK;  // next N*4 floats (idx as f32)

    int threads = 256;
    int blocks  = (n_nodes + threads - 1) / threads;
    segment_top4_kernel<<<blocks, threads, 0, stream>>>(
        row_ptr, scores, vals_out, idx_out, n_nodes);
}

// Round 3
// 149.675 us; speedup vs baseline: 1.2418x; 1.1300x over previous
//
#include <hip/hip_runtime.h>
#include <math.h>

#define TOPK 4
#define BLOCK 256
// Nodes/block = 256, mean edges/block = 8192 (Poisson, sigma ~90.5).
// CHUNK = 8704 covers mean + 5.7 sigma, so ~every block stages exactly once.
#define CHUNK 8704
#define LDS_FLOATS (CHUNK + 8)   // +pad so the unroll-by-4 tail over-read stays in bounds

__global__ __launch_bounds__(BLOCK) void segment_top4_kernel(
    const int* __restrict__ row_ptr,
    const float* __restrict__ scores,
    float* __restrict__ vals_out,   // [N,4] float32
    float* __restrict__ idx_out,    // [N,4] indices written as float32
    int n_nodes, int n_edges)
{
    __shared__ float lds_buf[LDS_FLOATS];

    int first = blockIdx.x * BLOCK;
    int node  = first + threadIdx.x;
    int last  = min(first + BLOCK, n_nodes);

    // Block-uniform edge range (single-line broadcast loads).
    int block_beg = row_ptr[first];
    int block_end = row_ptr[last];

    bool active = node < n_nodes;
    int seg_beg = active ? row_ptr[node]     : 0;
    int seg_end = active ? row_ptr[node + 1] : 0;

    float v0 = -INFINITY, v1 = -INFINITY, v2 = -INFINITY, v3 = -INFINITY;
    int   i0 = -1, i1 = -1, i2 = -1, i3 = -1;

    // Branchless insertion, strict '>' keeps the smaller edge index on ties
    // (matches reference). sc = -inf never inserts.
    auto ins = [&](float sc, int id) {
        bool g0 = sc > v0, g1 = sc > v1, g2 = sc > v2, g3 = sc > v3;
        v3 = g3 ? (g2 ? v2 : sc) : v3;  i3 = g3 ? (g2 ? i2 : id) : i3;
        v2 = g2 ? (g1 ? v1 : sc) : v2;  i2 = g2 ? (g1 ? i1 : id) : i2;
        v1 = g1 ? (g0 ? v0 : sc) : v1;  i1 = g1 ? (g0 ? i0 : id) : i1;
        v0 = g0 ? sc : v0;              i0 = g0 ? id : i0;
    };

    // Chunk loop (cbase stays 16-float aligned: initial &~15, CHUNK%16==0).
    for (int cbase = block_beg & ~15; cbase < block_end; cbase += CHUNK) {
        int cend = min(cbase + CHUNK, block_end);
        int n4   = (cend - cbase + 3) >> 2;   // float4s to stage
        // (n_edges%4==0 and cbase 16-aligned => never reads past the array)

        __syncthreads();   // previous chunk's readers done before overwrite
        for (int q = threadIdx.x; q < n4; q += BLOCK) {
            float4 f = *(const float4*)(scores + cbase + 4 * q);  // coalesced 16B/lane
            *(float4*)(lds_buf + 4 * q) = f;                      // conflict-free b128
        }
        __syncthreads();

        // Scan own segment from LDS, unrolled by 4 (independent ds_reads).
        int lo = max(seg_beg, cbase);
        int hi = min(seg_end, cend);
        for (int e = lo; e < hi; e += 4) {
            int l = e - cbase;
            float s0 = lds_buf[l];
            float s1 = lds_buf[l + 1];
            float s2 = lds_buf[l + 2];
            float s3 = lds_buf[l + 3];
            int rem = hi - e;
            ins(s0, e);
            ins(rem > 1 ? s1 : -INFINITY, e + 1);
            ins(rem > 2 ? s2 : -INFINITY, e + 2);
            ins(rem > 3 ? s3 : -INFINITY, e + 3);
        }
    }

    if (active) {
        float4 vout = make_float4(v0, v1, v2, v3);
        *(float4*)(vals_out + (size_t)node * 4) = vout;
        float4 iout = make_float4((float)i0, (float)i1, (float)i2, (float)i3);
        *(float4*)(idx_out + (size_t)node * 4) = iout;
    }
}

extern "C" void kernel_launch(void* const* d_in, const int* in_sizes, int n_in,
                              void* d_out, int out_size, void* d_ws, size_t ws_size,
                              hipStream_t stream)
{
    const int*   row_ptr = (const int*)d_in[0];
    const float* scores  = (const float*)d_in[1];
    int n_nodes = in_sizes[0] - 1;
    int n_edges = in_sizes[1];

    float* out      = (float*)d_out;
    float* vals_out = out;                           // first N*4 floats
    float* idx_out  = out + (size_t)n_nodes * TOPK;  // next N*4 floats (idx as f32)

    int blocks = (n_nodes + BLOCK - 1) / BLOCK;
    segment_top4_kernel<<<blocks, BLOCK, 0, stream>>>(
        row_ptr, scores, vals_out, idx_out, n_nodes, n_edges);
}

// Round 4
// 147.424 us; speedup vs baseline: 1.2607x; 1.0153x over previous
//
#include <hip/hip_runtime.h>
#include <math.h>

#define TOPK 4
#define BLOCK 64        // single-wave workgroups: 16 co-resident/CU, phases interleave
// 64 nodes/block, mean edges/block = 2048 (sigma ~45). CHUNK = 2368 = mean + 7 sigma,
// multiple of 16 (keeps cbase 16-float aligned across chunk iterations).
#define CHUNK 2368
// skewed layout: element l lives at l + (l>>5); max index CHUNK+2+(CHUNK+2)/32, +pad
#define LDS_FLOATS (CHUNK + CHUNK / 32 + 16)

__device__ __forceinline__ int skew(int l) { return l + (l >> 5); }

__global__ __launch_bounds__(BLOCK) void segment_top4_kernel(
    const int* __restrict__ row_ptr,
    const float* __restrict__ scores,
    float* __restrict__ vals_out,   // [N,4] float32
    float* __restrict__ idx_out,    // [N,4] indices written as float32
    int n_nodes)
{
    __shared__ float lds_buf[LDS_FLOATS];

    int first = blockIdx.x * BLOCK;
    int node  = first + threadIdx.x;
    int last  = min(first + BLOCK, n_nodes);

    int block_beg = row_ptr[first];
    int block_end = row_ptr[last];

    bool active = node < n_nodes;
    int seg_beg = active ? row_ptr[node]     : 0;
    int seg_end = active ? row_ptr[node + 1] : 0;

    float v0 = -INFINITY, v1 = -INFINITY, v2 = -INFINITY, v3 = -INFINITY;
    int   i0 = -1, i1 = -1, i2 = -1, i3 = -1;

    // Branchless insertion, strict '>' keeps the smaller edge index on ties
    // (matches reference). sc = -inf never inserts.
    auto ins = [&](float sc, int id) {
        bool g0 = sc > v0, g1 = sc > v1, g2 = sc > v2, g3 = sc > v3;
        v3 = g3 ? (g2 ? v2 : sc) : v3;  i3 = g3 ? (g2 ? i2 : id) : i3;
        v2 = g2 ? (g1 ? v1 : sc) : v2;  i2 = g2 ? (g1 ? i1 : id) : i2;
        v1 = g1 ? (g0 ? v0 : sc) : v1;  i1 = g1 ? (g0 ? i0 : id) : i1;
        v0 = g0 ? sc : v0;              i0 = g0 ? id : i0;
    };

    // Chunk loop runs exactly once for ~every block (CHUNK = mean + 7 sigma);
    // retained for correctness on pathological ranges.
    for (int cbase = block_beg & ~15; cbase < block_end; cbase += CHUNK) {
        int cend = min(cbase + CHUNK, block_end);
        int n4   = (cend - cbase + 3) >> 2;   // float4s to stage
        // cbase 16-aligned and E%16==0 => the (<=3 float) overread stays in-array

        __syncthreads();   // single-wave block: compiles to a cheap waitcnt(+barrier)
        for (int q = threadIdx.x; q < n4; q += BLOCK) {
            float4 f = *(const float4*)(scores + cbase + 4 * q);  // coalesced 16B/lane
            int l = 4 * q;
            // skewed b32 writes (stride-33 layout; <=4-way write aliasing, ~free)
            lds_buf[skew(l)]     = f.x;
            lds_buf[skew(l + 1)] = f.y;
            lds_buf[skew(l + 2)] = f.z;
            lds_buf[skew(l + 3)] = f.w;
        }
        __syncthreads();

        // Scan own segment from LDS; skewed addressing gives 2-way banks (free).
        int lo = max(seg_beg, cbase);
        int hi = min(seg_end, cend);
        for (int e = lo; e < hi; e += 4) {
            int l = e - cbase;
            float s0 = lds_buf[skew(l)];
            float s1 = lds_buf[skew(l + 1)];
            float s2 = lds_buf[skew(l + 2)];
            float s3 = lds_buf[skew(l + 3)];
            int rem = hi - e;
            ins(s0, e);
            ins(rem > 1 ? s1 : -INFINITY, e + 1);
            ins(rem > 2 ? s2 : -INFINITY, e + 2);
            ins(rem > 3 ? s3 : -INFINITY, e + 3);
        }
    }

    if (active) {
        float4 vout = make_float4(v0, v1, v2, v3);
        *(float4*)(vals_out + (size_t)node * 4) = vout;
        float4 iout = make_float4((float)i0, (float)i1, (float)i2, (float)i3);
        *(float4*)(idx_out + (size_t)node * 4) = iout;
    }
}

extern "C" void kernel_launch(void* const* d_in, const int* in_sizes, int n_in,
                              void* d_out, int out_size, void* d_ws, size_t ws_size,
                              hipStream_t stream)
{
    const int*   row_ptr = (const int*)d_in[0];
    const float* scores  = (const float*)d_in[1];
    int n_nodes = in_sizes[0] - 1;

    float* out      = (float*)d_out;
    float* vals_out = out;                           // first N*4 floats
    float* idx_out  = out + (size_t)n_nodes * TOPK;  // next N*4 floats (idx as f32)

    int blocks = (n_nodes + BLOCK - 1) / BLOCK;
    segment_top4_kernel<<<blocks, BLOCK, 0, stream>>>(
        row_ptr, scores, vals_out, idx_out, n_nodes);
}

// Round 5
// 145.628 us; speedup vs baseline: 1.2763x; 1.0123x over previous
//
#include <hip/hip_runtime.h>
#include <math.h>

#define TOPK 4
#define BLOCK 64        // single-wave workgroups
// 64 nodes/block, mean edges/block = 2048 (sigma ~45). CHUNK = 2304 = mean + 5.7
// sigma, multiple of 16 (keeps cbase 16-float aligned across chunk iterations).
#define CHUNK 2304
#define LDS_FLOATS (CHUNK + 8)  // +pad: scan's unroll-by-4 may read <=3 past hi

__global__ __launch_bounds__(BLOCK) void segment_top4_kernel(
    const int* __restrict__ row_ptr,
    const float* __restrict__ scores,
    float* __restrict__ vals_out,   // [N,4] float32
    float* __restrict__ idx_out,    // [N,4] indices written as float32
    int n_nodes)
{
    __shared__ float lds_buf[LDS_FLOATS];

    int first = blockIdx.x * BLOCK;
    int node  = first + threadIdx.x;
    int last  = min(first + BLOCK, n_nodes);

    int block_beg = row_ptr[first];
    int block_end = row_ptr[last];

    bool active = node < n_nodes;
    int seg_beg = active ? row_ptr[node]     : 0;
    int seg_end = active ? row_ptr[node + 1] : 0;

    float v0 = -INFINITY, v1 = -INFINITY, v2 = -INFINITY, v3 = -INFINITY;
    int   i0 = -1, i1 = -1, i2 = -1, i3 = -1;

    // Branchless insertion, strict '>' keeps the smaller edge index on ties
    // (matches reference). sc = -inf never inserts.
    auto ins = [&](float sc, int id) {
        bool g0 = sc > v0, g1 = sc > v1, g2 = sc > v2, g3 = sc > v3;
        v3 = g3 ? (g2 ? v2 : sc) : v3;  i3 = g3 ? (g2 ? i2 : id) : i3;
        v2 = g2 ? (g1 ? v1 : sc) : v2;  i2 = g2 ? (g1 ? i1 : id) : i2;
        v1 = g1 ? (g0 ? v0 : sc) : v1;  i1 = g1 ? (g0 ? i0 : id) : i1;
        v0 = g0 ? sc : v0;              i0 = g0 ? id : i0;
    };

    // Chunk loop runs exactly once for ~every block; kept for pathological ranges.
    for (int cbase = block_beg & ~15; cbase < block_end; cbase += CHUNK) {
        int cend = min(cbase + CHUNK, block_end);
        int n4   = (cend - cbase + 3) >> 2;    // float4s to stage
        int nit  = (n4 + BLOCK - 1) >> 6;      // 64-lane DMA rounds
        // cbase 16-aligned and E%16==0 => the (<=3 float) overread stays in-array

        __syncthreads();   // previous chunk's readers done before DMA overwrite
        // Fire-and-forget global->LDS DMA: all rounds issue with NO dependent
        // waitcnt between them (kills the serial ~900cyc/iter RTT chain).
        // LDS dest = wave-uniform base + lane*16, exactly our layout.
        for (int k = 0; k < nit; ++k) {
            int q = (k << 6) + threadIdx.x;
            if (q < n4) {
                __builtin_amdgcn_global_load_lds(
                    (const __attribute__((address_space(1))) void*)(scores + cbase + 4 * q),
                    (__attribute__((address_space(3))) void*)(lds_buf + (k << 8)),
                    16, 0, 0);
            }
        }
        __syncthreads();   // vmcnt(0) drain: DMA complete, LDS visible

        // Scan own segment from LDS, unrolled by 4 (independent ds_reads).
        int lo = max(seg_beg, cbase);
        int hi = min(seg_end, cend);
        for (int e = lo; e < hi; e += 4) {
            int l = e - cbase;
            float s0 = lds_buf[l];
            float s1 = lds_buf[l + 1];
            float s2 = lds_buf[l + 2];
            float s3 = lds_buf[l + 3];
            int rem = hi - e;
            ins(s0, e);
            ins(rem > 1 ? s1 : -INFINITY, e + 1);
            ins(rem > 2 ? s2 : -INFINITY, e + 2);
            ins(rem > 3 ? s3 : -INFINITY, e + 3);
        }
    }

    if (active) {
        float4 vout = make_float4(v0, v1, v2, v3);
        *(float4*)(vals_out + (size_t)node * 4) = vout;
        float4 iout = make_float4((float)i0, (float)i1, (float)i2, (float)i3);
        *(float4*)(idx_out + (size_t)node * 4) = iout;
    }
}

extern "C" void kernel_launch(void* const* d_in, const int* in_sizes, int n_in,
                              void* d_out, int out_size, void* d_ws, size_t ws_size,
                              hipStream_t stream)
{
    const int*   row_ptr = (const int*)d_in[0];
    const float* scores  = (const float*)d_in[1];
    int n_nodes = in_sizes[0] - 1;

    float* out      = (float*)d_out;
    float* vals_out = out;                           // first N*4 floats
    float* idx_out  = out + (size_t)n_nodes * TOPK;  // next N*4 floats (idx as f32)

    int blocks = (n_nodes + BLOCK - 1) / BLOCK;
    segment_top4_kernel<<<blocks, BLOCK, 0, stream>>>(
        row_ptr, scores, vals_out, idx_out, n_nodes);
}